// Round 7
// baseline (335.368 us; speedup 1.0000x reference)
//
#include <hip/hip_runtime.h>
#include <stdint.h>

#define K_DIM 1024
#define N_DIM 1024
#define NKT 16             // K / 64 k-tiles
#define WTILE 8192         // wq tile: 128 n-rows x 64 k int8
#define LDA 80             // fused-fallback LDS stride

typedef int v4i __attribute__((ext_vector_type(4)));

__device__ __forceinline__ int quant1(float f, float inv) {
    return (int)fminf(fmaxf(rintf(f * inv), -128.f), 127.f);
}
__device__ __forceinline__ uint32_t pack4(int a, int b, int c, int d) {
    return (uint32_t)(a & 255) | ((uint32_t)(b & 255) << 8) |
           ((uint32_t)(c & 255) << 16) | ((uint32_t)(d & 255) << 24);
}
// Swizzled byte offset inside a [rows][64] int8 tile: XOR bits 4-6 with (r&7).
// Bijective, 16B-alignment preserved; fragment reads (16 lanes, stride 64B,
// fixed 16B col) spread across all 8 four-bank groups. Proven in R3.
__device__ __forceinline__ int swz(int r, int c) {
    return (r * 64 + c) ^ ((r & 7) << 4);
}
__device__ __forceinline__ bool probe_x_is_f32(const void* xptr) {
    // even halfwords: bf16/f16-origin data decodes mostly into [2^-3, 2);
    // f32-widened x has lo halfwords = mantissa<<13, ~none in range.
    const uint16_t* xu = (const uint16_t*)xptr;
    int lane = (int)(threadIdx.x & 63);
    float pv = __uint_as_float(((uint32_t)xu[2 * lane]) << 16);
    float pa = fabsf(pv);
    unsigned long long mx = __ballot(pa >= 0.125f && pa < 2.0f);
    return (__popcll(mx) < 32);
}

// ================= weight pre-pack: int32 -> int8, swizzled tiles ===========
__global__ __launch_bounds__(256) void prep_w_kernel(
    const int* __restrict__ w32, uint8_t* __restrict__ wq)
{
    int c = blockIdx.x * 256 + threadIdx.x;   // [0, 65536) 16-elem chunks
    int q = c & 3;
    int r = (c >> 2) & 127;
    int t = c >> 9;                           // nblk*16 + kb
    size_t row = (size_t)(t >> 4) * 128 + r;
    int    col = (t & 15) * 64 + q * 16;
    const int4* src = (const int4*)(w32 + row * K_DIM + col);
    uint32_t pk[4];
#pragma unroll
    for (int g = 0; g < 4; g++) {
        int4 v = src[g];
        pk[g] = pack4(v.x, v.y, v.z, v.w);
    }
    *(uint4*)(wq + ((size_t)t << 13) + swz(r, q * 16)) =
        make_uint4(pk[0], pk[1], pk[2], pk[3]);
}

// ================= fused quant + GEMM (BM=32, 4 blocks/CU) ==================
// Block owns x rows [mblk*32, +32): quantizes them ONCE into a 32KB LDS panel
// (overlapped with n-pass 0), then passes 1..7 reuse it barrier-free with a
// 3-slot register rotation on the wq fragments (prefetch distance 2).
template<bool X_F32>
__device__ __forceinline__ void fused_body(
    uint8_t (*lA)[2048],                       // [NKT][32 rows x 64B], swizzled
    const void* __restrict__ xptr,
    const uint8_t* __restrict__ wq,
    const float* __restrict__ wscale,
    const float s,
    const float* __restrict__ bias,
    float* __restrict__ out)
{
    const int tid  = threadIdx.x;
    const int lane = tid & 63;
    const int wn   = tid >> 6;           // wave 0..3 -> 32-col band
    const int quad = lane >> 4;
    const int l16  = lane & 15;

    const int mblk = (int)blockIdx.x;
    const int m0   = mblk * 32;
    const float inv = 1.0f / s;

    // quant mapping: 256 threads cover a PAIR of k-tiles per step
    const int qkt = tid >> 7;            // tile offset within pair (0/1)
    const int qr  = (tid >> 2) & 31;     // row 0..31
    const int qc  = (tid & 3) * 16;      // 16-elem chunk
    const int wdst = swz(qr, qc);

    const float*    xbf = (const float*)xptr    + (size_t)(m0 + qr) * K_DIM + qc;
    const uint16_t* xbh = (const uint16_t*)xptr + (size_t)(m0 + qr) * K_DIM + qc;

    int offA[2], offB[2];
#pragma unroll
    for (int mt = 0; mt < 2; mt++) offA[mt] = swz(mt * 16 + l16, quad * 16);
#pragma unroll
    for (int nt = 0; nt < 2; nt++) offB[nt] = swz(wn * 32 + nt * 16 + l16, quad * 16);

    // quantize tile pair s (tiles 2s, 2s+1): one tile per half-block
#define QUANT_PAIR(S)                                                          \
    {                                                                          \
        const int kt = 2 * (S) + qkt;                                          \
        uint32_t pk[4];                                                        \
        if (X_F32) {                                                           \
            const float4* s4 = (const float4*)(xbf + kt * 64);                 \
            float4 a = s4[0], b = s4[1], c = s4[2], d = s4[3];                 \
            pk[0] = pack4(quant1(a.x,inv),quant1(a.y,inv),quant1(a.z,inv),quant1(a.w,inv)); \
            pk[1] = pack4(quant1(b.x,inv),quant1(b.y,inv),quant1(b.z,inv),quant1(b.w,inv)); \
            pk[2] = pack4(quant1(c.x,inv),quant1(c.y,inv),quant1(c.z,inv),quant1(c.w,inv)); \
            pk[3] = pack4(quant1(d.x,inv),quant1(d.y,inv),quant1(d.z,inv),quant1(d.w,inv)); \
        } else {                                                               \
            const uint4* s4 = (const uint4*)(xbh + kt * 64);                   \
            union { uint4 v[2]; uint32_t u[8]; } ax;                           \
            ax.v[0] = s4[0]; ax.v[1] = s4[1];                                  \
            _Pragma("unroll")                                                  \
            for (int i = 0; i < 4; i++) {                                      \
                uint32_t wa = ax.u[2*i], wb = ax.u[2*i+1];                     \
                pk[i] = pack4(quant1(__uint_as_float(wa << 16), inv),          \
                              quant1(__uint_as_float(wa & 0xffff0000u), inv),  \
                              quant1(__uint_as_float(wb << 16), inv),          \
                              quant1(__uint_as_float(wb & 0xffff0000u), inv)); \
            }                                                                  \
        }                                                                      \
        *(uint4*)&lA[kt][wdst] = make_uint4(pk[0], pk[1], pk[2], pk[3]);       \
    }

    // ---- prologue: tiles 0..3 ----
    QUANT_PAIR(0)
    QUANT_PAIR(1)
    __syncthreads();

    // ---- n-pass 0: compute + progressive quant of tiles 4..15 ----
    {
        v4i acc[2][2] = {};
#pragma unroll
        for (int kb = 0; kb < NKT; kb++) {
            v4i bf[2], af[2];
#pragma unroll
            for (int nt = 0; nt < 2; nt++)
                bf[nt] = *(const v4i*)(wq + (size_t)kb * WTILE + offB[nt]);
            af[0] = *(const v4i*)&lA[kb][offA[0]];
            af[1] = *(const v4i*)&lA[kb][offA[1]];
#pragma unroll
            for (int mt = 0; mt < 2; mt++)
#pragma unroll
                for (int nt = 0; nt < 2; nt++)
                    acc[mt][nt] = __builtin_amdgcn_mfma_i32_16x16x64_i8(
                        af[mt], bf[nt], acc[mt][nt], 0, 0, 0);
            if (kb < 6) {                 // all 16 tiles written by iter 5
                QUANT_PAIR(kb + 2)        // tiles 4+2kb, 5+2kb (used >= iter 4+2kb)
                __syncthreads();
            }
        }
        float osc[2], obi[2];
#pragma unroll
        for (int nt = 0; nt < 2; nt++) {
            int col = wn * 32 + nt * 16 + l16;
            osc[nt] = s * wscale[col];
            obi[nt] = bias[col];
        }
#pragma unroll
        for (int mt = 0; mt < 2; mt++) {
            int rowb = m0 + mt * 16 + quad * 4;
#pragma unroll
            for (int nt = 0; nt < 2; nt++) {
                int col = wn * 32 + nt * 16 + l16;
#pragma unroll
                for (int r = 0; r < 4; r++)
                    out[(size_t)(rowb + r) * N_DIM + col] =
                        (float)acc[mt][nt][r] * osc[nt] + obi[nt];
            }
        }
    }

    // ---- n-passes 1..7: barrier-free, 3-slot wq register rotation ----
    for (int np = 1; np < 8; np++) {
        const uint8_t* wbase = wq + (size_t)np * (NKT * WTILE);
        v4i bfb[3][2];                     // static-indexed after full unroll
#pragma unroll
        for (int nt = 0; nt < 2; nt++) {
            bfb[0][nt] = *(const v4i*)(wbase + 0 * WTILE + offB[nt]);
            bfb[1][nt] = *(const v4i*)(wbase + 1 * WTILE + offB[nt]);
        }
        v4i acc[2][2] = {};
#pragma unroll
        for (int kb = 0; kb < NKT; kb++) {
            if (kb + 2 < NKT) {            // issue kb+2 BEFORE kb's MFMAs
#pragma unroll
                for (int nt = 0; nt < 2; nt++)
                    bfb[(kb + 2) % 3][nt] =
                        *(const v4i*)(wbase + (size_t)(kb + 2) * WTILE + offB[nt]);
            }
            v4i af[2];
            af[0] = *(const v4i*)&lA[kb][offA[0]];
            af[1] = *(const v4i*)&lA[kb][offA[1]];
#pragma unroll
            for (int mt = 0; mt < 2; mt++)
#pragma unroll
                for (int nt = 0; nt < 2; nt++)
                    acc[mt][nt] = __builtin_amdgcn_mfma_i32_16x16x64_i8(
                        af[mt], bfb[kb % 3][nt], acc[mt][nt], 0, 0, 0);
        }
        const int n0 = np * 128;
        float osc[2], obi[2];
#pragma unroll
        for (int nt = 0; nt < 2; nt++) {
            int col = n0 + wn * 32 + nt * 16 + l16;
            osc[nt] = s * wscale[col];
            obi[nt] = bias[col];
        }
#pragma unroll
        for (int mt = 0; mt < 2; mt++) {
            int rowb = m0 + mt * 16 + quad * 4;
#pragma unroll
            for (int nt = 0; nt < 2; nt++) {
                int col = n0 + wn * 32 + nt * 16 + l16;
#pragma unroll
                for (int r = 0; r < 4; r++)
                    out[(size_t)(rowb + r) * N_DIM + col] =
                        (float)acc[mt][nt][r] * osc[nt] + obi[nt];
            }
        }
    }
#undef QUANT_PAIR
}

__global__ __launch_bounds__(256, 4) void fused_gemm_kernel(
    const void* __restrict__ xptr,
    const uint8_t* __restrict__ wq,
    const float* __restrict__ wscale,
    const float* __restrict__ ascale_p,
    const float* __restrict__ bias,
    float* __restrict__ out)
{
    __shared__ uint8_t lA[NKT][2048];    // 32 KB -> 4 blocks/CU
    const bool x_is_f32 = probe_x_is_f32(xptr);
    const float s = ascale_p[0];
    if (x_is_f32) fused_body<true >(lA, xptr, wq, wscale, s, bias, out);
    else          fused_body<false>(lA, xptr, wq, wscale, s, bias, out);
}

// ================= fallback: proven fused kernel (R0, 655 us) ===============
template<bool X_F32>
__device__ __forceinline__ void gemm_body(
    int8_t* lA, int8_t* lB,
    const void* __restrict__ xptr,
    const int* __restrict__ w32,
    const float* __restrict__ wscale,
    const float s,
    const float* __restrict__ bias,
    float* __restrict__ out)
{
    const int tid  = threadIdx.x;
    const int lane = tid & 63;
    const int wave = tid >> 6;
    const int wm   = wave >> 1;
    const int wn   = wave & 1;
    const int quad = lane >> 4;
    const int l16  = lane & 15;

    const int mblk = (int)blockIdx.x >> 3;
    const int nblk = (int)blockIdx.x & 7;
    const int m0 = mblk * 128;
    const int n0 = nblk * 128;

    const float inv = 1.0f / s;
    const int ar = tid >> 1;
    const int ah = (tid & 1) * 32;

    const float*    xrowf = (const float*)xptr    + (size_t)(m0 + ar) * K_DIM + ah;
    const uint16_t* xrowh = (const uint16_t*)xptr + (size_t)(m0 + ar) * K_DIM + ah;
    const int*      wrow  = w32 + (size_t)(n0 + ar) * K_DIM + ah;

    v4i acc[4][4] = {};

    for (int kb = 0; kb < K_DIM; kb += 64) {
        {
            uint32_t pk[8];
            if (X_F32) {
                const float4* xs = (const float4*)(xrowf + kb);
#pragma unroll
                for (int g = 0; g < 8; g++) {
                    float4 v = xs[g];
                    pk[g] = pack4(quant1(v.x, inv), quant1(v.y, inv),
                                  quant1(v.z, inv), quant1(v.w, inv));
                }
            } else {
                const uint4* xs = (const uint4*)(xrowh + kb);
                union { uint4 v[4]; uint32_t u[16]; } ax;
                ax.v[0] = xs[0]; ax.v[1] = xs[1]; ax.v[2] = xs[2]; ax.v[3] = xs[3];
#pragma unroll
                for (int i = 0; i < 8; i++) {
                    uint32_t wa = ax.u[2 * i], wb = ax.u[2 * i + 1];
                    pk[i] = pack4(quant1(__uint_as_float(wa << 16), inv),
                                  quant1(__uint_as_float(wa & 0xffff0000u), inv),
                                  quant1(__uint_as_float(wb << 16), inv),
                                  quant1(__uint_as_float(wb & 0xffff0000u), inv));
                }
            }
            uint4* adst = (uint4*)&lA[ar * LDA + ah];
            adst[0] = make_uint4(pk[0], pk[1], pk[2], pk[3]);
            adst[1] = make_uint4(pk[4], pk[5], pk[6], pk[7]);
        }
        {
            const int4* ws4 = (const int4*)(wrow + kb);
            uint32_t pb[8];
#pragma unroll
            for (int g = 0; g < 8; g++) {
                int4 v = ws4[g];
                pb[g] = pack4(v.x, v.y, v.z, v.w);
            }
            uint4* bdst = (uint4*)&lB[ar * LDA + ah];
            bdst[0] = make_uint4(pb[0], pb[1], pb[2], pb[3]);
            bdst[1] = make_uint4(pb[4], pb[5], pb[6], pb[7]);
        }
        __syncthreads();

        v4i af[4], bf[4];
#pragma unroll
        for (int mt = 0; mt < 4; mt++)
            af[mt] = *(const v4i*)&lA[(wm * 64 + mt * 16 + l16) * LDA + quad * 16];
#pragma unroll
        for (int nt = 0; nt < 4; nt++)
            bf[nt] = *(const v4i*)&lB[(wn * 64 + nt * 16 + l16) * LDA + quad * 16];
#pragma unroll
        for (int mt = 0; mt < 4; mt++)
#pragma unroll
            for (int nt = 0; nt < 4; nt++)
                acc[mt][nt] = __builtin_amdgcn_mfma_i32_16x16x64_i8(af[mt], bf[nt], acc[mt][nt], 0, 0, 0);
        __syncthreads();
    }

    float osc[4], obi[4];
#pragma unroll
    for (int nt = 0; nt < 4; nt++) {
        int col = n0 + wn * 64 + nt * 16 + l16;
        osc[nt] = s * wscale[col];
        obi[nt] = bias[col];
    }
#pragma unroll
    for (int mt = 0; mt < 4; mt++) {
        int rowb = m0 + wm * 64 + mt * 16 + quad * 4;
#pragma unroll
        for (int nt = 0; nt < 4; nt++) {
            int col = n0 + wn * 64 + nt * 16 + l16;
#pragma unroll
            for (int r = 0; r < 4; r++) {
                out[(size_t)(rowb + r) * N_DIM + col] =
                    (float)acc[mt][nt][r] * osc[nt] + obi[nt];
            }
        }
    }
}

__global__ __launch_bounds__(256, 2) void int8_linear_fused(
    const void* __restrict__ xptr,
    const int* __restrict__ w32,
    const float* __restrict__ wscale,
    const float* __restrict__ ascale_p,
    const float* __restrict__ bias,
    float* __restrict__ out)
{
    __shared__ int8_t lA[128 * LDA];
    __shared__ int8_t lB[128 * LDA];
    const bool x_is_f32 = probe_x_is_f32(xptr);
    const float s = ascale_p[0];
    if (x_is_f32) gemm_body<true >(lA, lB, xptr, w32, wscale, s, bias, out);
    else          gemm_body<false>(lA, lB, xptr, w32, wscale, s, bias, out);
}

// ================= launch ===================================================
extern "C" void kernel_launch(void* const* d_in, const int* in_sizes, int n_in,
                              void* d_out, int out_size, void* d_ws, size_t ws_size,
                              hipStream_t stream) {
    const void*  xptr   = d_in[0];              // f16 widened to f32 by harness
    const int*   w32    = (const int*)d_in[1];  // int8 widened to int32
    const float* wscale = (const float*)d_in[2];
    const float* ascale = (const float*)d_in[3];
    const float* bias   = (const float*)d_in[4];
    float*       out    = (float*)d_out;        // f16 output -> float*

    int M = in_sizes[0] / K_DIM;                // 32768
    size_t need = (size_t)N_DIM * K_DIM;        // wq only: 1 MB

    bool split_ok = (d_ws != nullptr) && (ws_size >= need) && (M == 32768);

    if (split_ok) {
        uint8_t* wq = (uint8_t*)d_ws;
        prep_w_kernel<<<dim3(256), 256, 0, stream>>>(w32, wq);
        fused_gemm_kernel<<<dim3(M / 32), 256, 0, stream>>>(
            xptr, wq, wscale, ascale, bias, out);
    } else {
        dim3 grid((M / 128) * (N_DIM / 128));
        int8_linear_fused<<<grid, 256, 0, stream>>>(
            xptr, w32, wscale, ascale, bias, out);
    }
}

// Round 8
// 269.605 us; speedup vs baseline: 1.2439x; 1.2439x over previous
//
#include <hip/hip_runtime.h>
#include <stdint.h>

#define K_DIM 1024
#define N_DIM 1024
#define BM 128
#define BN 128
#define BK 64
#define NKT (K_DIM / BK)          // 16 K-tiles
#define TILE_BYTES (BM * BK)      // 8192 B per (row-block, k-tile)
#define W_BLOCKS 256              // weight-pack blocks in prep kernel
#define XQ_BLOCKS 2048            // x-quant grid-stride blocks in prep kernel
#define LDA 80                    // fused-fallback LDS stride

typedef int v4i __attribute__((ext_vector_type(4)));

__device__ __forceinline__ int quant1(float f, float inv) {
    return (int)fminf(fmaxf(rintf(f * inv), -128.f), 127.f);
}
__device__ __forceinline__ uint32_t pack4(int a, int b, int c, int d) {
    return (uint32_t)(a & 255) | ((uint32_t)(b & 255) << 8) |
           ((uint32_t)(c & 255) << 16) | ((uint32_t)(d & 255) << 24);
}
// Swizzled byte offset inside an 8 KB tile: row r in [0,128), col c in [0,64).
// XOR bits 4-6 with (r&7): bijective, 16B-alignment preserved. Fragment reads
// (16 lanes, stride 64B, fixed 16B col) spread across all 8 four-bank groups.
// Proven R3.
__device__ __forceinline__ int swz(int r, int c) {
    return (r * BK + c) ^ ((r & 7) << 4);
}
__device__ __forceinline__ bool probe_x_is_f32(const void* xptr) {
    // even halfwords: bf16/f16-origin data decodes mostly into [2^-3, 2);
    // f32-widened x has lo halfwords = mantissa<<13, ~none in range.
    const uint16_t* xu = (const uint16_t*)xptr;
    int lane = (int)(threadIdx.x & 63);
    float pv = __uint_as_float(((uint32_t)xu[2 * lane]) << 16);
    float pa = fabsf(pv);
    unsigned long long mx = __ballot(pa >= 0.125f && pa < 2.0f);
    return (__popcll(mx) < 32);
}

// ================= split path: prep (quantize + pack, swizzled tiles) =======
// Exactly the R3-proven kernel (270 us run).
__global__ __launch_bounds__(256) void prep_kernel(
    const void* __restrict__ xptr,
    const int*  __restrict__ w32,
    const float* __restrict__ ascale_p,
    uint8_t* __restrict__ xq,
    uint8_t* __restrict__ wq,
    int M)
{
    const float inv = 1.0f / ascale_p[0];
    const int tid = threadIdx.x;

    if (blockIdx.x < W_BLOCKS) {
        // weight pack: 256 blocks x 256 threads x 16 elems = 1M elems, once
        int c = blockIdx.x * 256 + tid;           // [0, 65536)
        int q = c & 3;                            // 16-col chunk within k-tile
        int r = (c >> 2) & 127;                   // row within tile
        int t = c >> 9;                           // nblk*NKT + kb, [0,128)
        size_t row = (size_t)(t >> 4) * BM + r;
        int    col = (t & 15) * BK + q * 16;
        const int4* src = (const int4*)(w32 + row * K_DIM + col);
        uint32_t pk[4];
#pragma unroll
        for (int g = 0; g < 4; g++) {
            int4 v = src[g];
            pk[g] = pack4(v.x, v.y, v.z, v.w);
        }
        *(uint4*)(wq + ((size_t)t << 13) + swz(r, q * 16)) =
            make_uint4(pk[0], pk[1], pk[2], pk[3]);
        return;
    }

    const bool x_is_f32 = probe_x_is_f32(xptr);
    const int XC = M * (K_DIM / 16);              // total 16-elem chunks
    const int stride = XQ_BLOCKS * 256;
    for (int c = (blockIdx.x - W_BLOCKS) * 256 + tid; c < XC; c += stride) {
        int q = c & 3;
        int r = (c >> 2) & 127;
        int t = c >> 9;                           // mblk*NKT + kb
        size_t row = (size_t)(t >> 4) * BM + r;
        int    col = (t & 15) * BK + q * 16;
        uint32_t pk[4];
        if (x_is_f32) {
            const float4* src = (const float4*)((const float*)xptr + row * K_DIM + col);
#pragma unroll
            for (int g = 0; g < 4; g++) {
                float4 v = src[g];
                pk[g] = pack4(quant1(v.x, inv), quant1(v.y, inv),
                              quant1(v.z, inv), quant1(v.w, inv));
            }
        } else {
            const uint4* src = (const uint4*)((const uint16_t*)xptr + row * K_DIM + col);
            union { uint4 v[2]; uint32_t u[8]; } ax;
            ax.v[0] = src[0]; ax.v[1] = src[1];
#pragma unroll
            for (int i = 0; i < 4; i++) {
                uint32_t wa = ax.u[2 * i], wb = ax.u[2 * i + 1];
                pk[i] = pack4(quant1(__uint_as_float(wa << 16), inv),
                              quant1(__uint_as_float(wa & 0xffff0000u), inv),
                              quant1(__uint_as_float(wb << 16), inv),
                              quant1(__uint_as_float(wb & 0xffff0000u), inv));
            }
        }
        *(uint4*)(xq + ((size_t)t << 13) + swz(r, q * 16)) =
            make_uint4(pk[0], pk[1], pk[2], pk[3]);
    }
}

// ================= split path: GEMM =========================================
// R3 structure, minus B-LDS staging: A staged via global_load_lds (2-buffer,
// proven); B fragments loaded DIRECT from L2-resident pre-swizzled wq with a
// 2-slot register rotation (addressing proven in R5). Halves the per-step
// barrier-guarded staging volume and halves LDS (16 KB).
#define GLOAD16(gsrc, ldst) \
    __builtin_amdgcn_global_load_lds( \
        (const __attribute__((address_space(1))) uint32_t*)(const void*)(gsrc), \
        (__attribute__((address_space(3))) uint32_t*)(void*)(ldst), 16, 0, 0)

__global__ __launch_bounds__(256, 4) void int8_gemm_kernel(
    const uint8_t* __restrict__ xq,
    const uint8_t* __restrict__ wq,
    const float* __restrict__ wscale,
    const float* __restrict__ ascale_p,
    const float* __restrict__ bias,
    float* __restrict__ out)
{
    __shared__ uint8_t lA[2][TILE_BYTES];   // 16 KB total

    const int tid  = threadIdx.x;
    const int lane = tid & 63;
    const int wave = tid >> 6;
    const int wm   = wave >> 1;
    const int wn   = wave & 1;
    const int quad = lane >> 4;
    const int l16  = lane & 15;

    // bijective XCD swizzle (grid = numm*8): each XCD gets a contiguous mblk
    // range; all 8 n-blocks of one x panel share an L2.
    const int numm = (int)gridDim.x >> 3;
    const int logical = ((int)blockIdx.x & 7) * numm + ((int)blockIdx.x >> 3);
    const int mblk = logical >> 3;
    const int nblk = logical & 7;

    const uint8_t* srcA = xq + (size_t)mblk * (NKT * TILE_BYTES) + tid * 16;
    const uint8_t* wpan = wq + (size_t)nblk * (NKT * TILE_BYTES);

    int offA[4], offB[4];
#pragma unroll
    for (int i = 0; i < 4; i++) {
        offA[i] = swz(wm * 64 + i * 16 + l16, quad * 16);
        offB[i] = swz(wn * 64 + i * 16 + l16, quad * 16);
    }

    v4i acc[4][4] = {};

    // prologue: stage A tile 0 (8 KB, per-wave dest = base + lane*16);
    // prefetch B fragments for kb=0 into rotation slot 0.
    GLOAD16(srcA,        &lA[0][tid * 16]);
    GLOAD16(srcA + 4096, &lA[0][4096 + tid * 16]);
    v4i bfb[2][4];
#pragma unroll
    for (int nt = 0; nt < 4; nt++)
        bfb[0][nt] = *(const v4i*)(wpan + offB[nt]);

    // full unroll -> bfb indices static (rule #20)
#pragma unroll
    for (int kb = 0; kb < NKT; kb++) {
        __syncthreads();                   // lA[kb&1] ready (compiler drains)
        if (kb + 1 < NKT) {
            const uint8_t* sa = srcA + (size_t)(kb + 1) * TILE_BYTES;
            GLOAD16(sa,        &lA[(kb + 1) & 1][tid * 16]);
            GLOAD16(sa + 4096, &lA[(kb + 1) & 1][4096 + tid * 16]);
            const uint8_t* wt = wpan + (size_t)(kb + 1) * TILE_BYTES;
#pragma unroll
            for (int nt = 0; nt < 4; nt++)
                bfb[(kb + 1) & 1][nt] = *(const v4i*)(wt + offB[nt]);
        }
        v4i af[4];
#pragma unroll
        for (int mt = 0; mt < 4; mt++)
            af[mt] = *(const v4i*)&lA[kb & 1][offA[mt]];
#pragma unroll
        for (int mt = 0; mt < 4; mt++)
#pragma unroll
            for (int nt = 0; nt < 4; nt++)
                acc[mt][nt] = __builtin_amdgcn_mfma_i32_16x16x64_i8(
                    af[mt], bfb[kb & 1][nt], acc[mt][nt], 0, 0, 0);
    }

    // epilogue: dequant + bias (C/D: col = l16, row = quad*4 + r)
    const float s = ascale_p[0];
    const int m0 = mblk * BM, n0 = nblk * BN;
    float osc[4], obi[4];
#pragma unroll
    for (int nt = 0; nt < 4; nt++) {
        int col = n0 + wn * 64 + nt * 16 + l16;
        osc[nt] = s * wscale[col];
        obi[nt] = bias[col];
    }
#pragma unroll
    for (int mt = 0; mt < 4; mt++) {
        int rowb = m0 + wm * 64 + mt * 16 + quad * 4;
#pragma unroll
        for (int nt = 0; nt < 4; nt++) {
            int col = n0 + wn * 64 + nt * 16 + l16;
#pragma unroll
            for (int r = 0; r < 4; r++) {
                out[(size_t)(rowb + r) * N_DIM + col] =
                    (float)acc[mt][nt][r] * osc[nt] + obi[nt];
            }
        }
    }
}

// ================= fallback: proven fused kernel (R0, 655 us) ===============
template<bool X_F32>
__device__ __forceinline__ void gemm_body(
    int8_t* lA, int8_t* lB,
    const void* __restrict__ xptr,
    const int* __restrict__ w32,
    const float* __restrict__ wscale,
    const float s,
    const float* __restrict__ bias,
    float* __restrict__ out)
{
    const int tid  = threadIdx.x;
    const int lane = tid & 63;
    const int wave = tid >> 6;
    const int wm   = wave >> 1;
    const int wn   = wave & 1;
    const int quad = lane >> 4;
    const int l16  = lane & 15;

    const int mblk = (int)blockIdx.x >> 3;
    const int nblk = (int)blockIdx.x & 7;
    const int m0 = mblk * BM;
    const int n0 = nblk * BN;

    const float inv = 1.0f / s;
    const int ar = tid >> 1;
    const int ah = (tid & 1) * 32;

    const float*    xrowf = (const float*)xptr    + (size_t)(m0 + ar) * K_DIM + ah;
    const uint16_t* xrowh = (const uint16_t*)xptr + (size_t)(m0 + ar) * K_DIM + ah;
    const int*      wrow  = w32 + (size_t)(n0 + ar) * K_DIM + ah;

    v4i acc[4][4] = {};

    for (int kb = 0; kb < K_DIM; kb += BK) {
        {
            uint32_t pk[8];
            if (X_F32) {
                const float4* xs = (const float4*)(xrowf + kb);
#pragma unroll
                for (int g = 0; g < 8; g++) {
                    float4 v = xs[g];
                    pk[g] = pack4(quant1(v.x, inv), quant1(v.y, inv),
                                  quant1(v.z, inv), quant1(v.w, inv));
                }
            } else {
                const uint4* xs = (const uint4*)(xrowh + kb);
                union { uint4 v[4]; uint32_t u[16]; } ax;
                ax.v[0] = xs[0]; ax.v[1] = xs[1]; ax.v[2] = xs[2]; ax.v[3] = xs[3];
#pragma unroll
                for (int i = 0; i < 8; i++) {
                    uint32_t wa = ax.u[2 * i], wb = ax.u[2 * i + 1];
                    pk[i] = pack4(quant1(__uint_as_float(wa << 16), inv),
                                  quant1(__uint_as_float(wa & 0xffff0000u), inv),
                                  quant1(__uint_as_float(wb << 16), inv),
                                  quant1(__uint_as_float(wb & 0xffff0000u), inv));
                }
            }
            uint4* adst = (uint4*)&lA[ar * LDA + ah];
            adst[0] = make_uint4(pk[0], pk[1], pk[2], pk[3]);
            adst[1] = make_uint4(pk[4], pk[5], pk[6], pk[7]);
        }
        {
            const int4* ws4 = (const int4*)(wrow + kb);
            uint32_t pb[8];
#pragma unroll
            for (int g = 0; g < 8; g++) {
                int4 v = ws4[g];
                pb[g] = pack4(v.x, v.y, v.z, v.w);
            }
            uint4* bdst = (uint4*)&lB[ar * LDA + ah];
            bdst[0] = make_uint4(pb[0], pb[1], pb[2], pb[3]);
            bdst[1] = make_uint4(pb[4], pb[5], pb[6], pb[7]);
        }
        __syncthreads();

        v4i af[4], bf[4];
#pragma unroll
        for (int mt = 0; mt < 4; mt++)
            af[mt] = *(const v4i*)&lA[(wm * 64 + mt * 16 + l16) * LDA + quad * 16];
#pragma unroll
        for (int nt = 0; nt < 4; nt++)
            bf[nt] = *(const v4i*)&lB[(wn * 64 + nt * 16 + l16) * LDA + quad * 16];
#pragma unroll
        for (int mt = 0; mt < 4; mt++)
#pragma unroll
            for (int nt = 0; nt < 4; nt++)
                acc[mt][nt] = __builtin_amdgcn_mfma_i32_16x16x64_i8(af[mt], bf[nt], acc[mt][nt], 0, 0, 0);
        __syncthreads();
    }

    float osc[4], obi[4];
#pragma unroll
    for (int nt = 0; nt < 4; nt++) {
        int col = n0 + wn * 64 + nt * 16 + l16;
        osc[nt] = s * wscale[col];
        obi[nt] = bias[col];
    }
#pragma unroll
    for (int mt = 0; mt < 4; mt++) {
        int rowb = m0 + wm * 64 + mt * 16 + quad * 4;
#pragma unroll
        for (int nt = 0; nt < 4; nt++) {
            int col = n0 + wn * 64 + nt * 16 + l16;
#pragma unroll
            for (int r = 0; r < 4; r++) {
                out[(size_t)(rowb + r) * N_DIM + col] =
                    (float)acc[mt][nt][r] * osc[nt] + obi[nt];
            }
        }
    }
}

__global__ __launch_bounds__(256, 2) void int8_linear_fused(
    const void* __restrict__ xptr,
    const int* __restrict__ w32,
    const float* __restrict__ wscale,
    const float* __restrict__ ascale_p,
    const float* __restrict__ bias,
    float* __restrict__ out)
{
    __shared__ int8_t lA[BM * LDA];
    __shared__ int8_t lB[BN * LDA];
    const bool x_is_f32 = probe_x_is_f32(xptr);
    const float s = ascale_p[0];
    if (x_is_f32) gemm_body<true >(lA, lB, xptr, w32, wscale, s, bias, out);
    else          gemm_body<false>(lA, lB, xptr, w32, wscale, s, bias, out);
}

// ================= launch ===================================================
extern "C" void kernel_launch(void* const* d_in, const int* in_sizes, int n_in,
                              void* d_out, int out_size, void* d_ws, size_t ws_size,
                              hipStream_t stream) {
    const void*  xptr   = d_in[0];              // f16 widened to f32 by harness
    const int*   w32    = (const int*)d_in[1];  // int8 widened to int32
    const float* wscale = (const float*)d_in[2];
    const float* ascale = (const float*)d_in[3];
    const float* bias   = (const float*)d_in[4];
    float*       out    = (float*)d_out;        // f16 output -> float*

    int M = in_sizes[0] / K_DIM;                // 32768
    size_t need = (size_t)M * K_DIM + (size_t)N_DIM * K_DIM;  // 34.6 MB

    bool split_ok = (d_ws != nullptr) && (ws_size >= need) &&
                    (M == 32768) && (M % BM == 0);

    if (split_ok) {
        uint8_t* xq = (uint8_t*)d_ws;
        uint8_t* wq = xq + (size_t)M * K_DIM;
        prep_kernel<<<dim3(W_BLOCKS + XQ_BLOCKS), 256, 0, stream>>>(
            xptr, w32, ascale, xq, wq, M);
        int numm = M / BM;
        int8_gemm_kernel<<<dim3(numm * 8), 256, 0, stream>>>(
            xq, wq, wscale, ascale, bias, out);
    } else {
        dim3 grid((M / BM) * (N_DIM / BN));     // 2048 blocks
        int8_linear_fused<<<grid, 256, 0, stream>>>(
            xptr, w32, wscale, ascale, bias, out);
    }
}